// Round 1
// baseline (18031.610 us; speedup 1.0000x reference)
//
#include <hip/hip_runtime.h>
#include <math.h>

#define H    1024
#define H3   3072
#define DIN  512
#define VSZ  32000
#define SS   64
#define BB   128
#define TT   48
#define TP   47
#define NROWS (TP*BB)      // 6016
#define VCHUNKS 125        // 32000 / 256
#define FMARGIN 0.1f

// ---------- small helpers ----------

__global__ __launch_bounds__(128) void k_mask_sum(const float* __restrict__ mask, float* __restrict__ msum){
    int b = threadIdx.x;
    if (b < BB){ float s = 0.f; for (int i = 0; i < SS; i++) s += mask[i*BB + b]; msum[b] = s; }
}

__global__ __launch_bounds__(256) void k_mean_ctx(const float* __restrict__ ctx, const float* __restrict__ msum,
                                                  float* __restrict__ mean){
    int idx = blockIdx.x*256 + threadIdx.x;       // b*H + h
    if (idx < BB*H){
        float s = 0.f;
        for (int i = 0; i < SS; i++) s += ctx[(size_t)i*BB*H + idx];
        mean[idx] = s / msum[idx / H];
    }
}

__global__ __launch_bounds__(256) void k_wout_norm(const float* __restrict__ W, float* __restrict__ invn){
    int wave = threadIdx.x >> 6, lane = threadIdx.x & 63;
    int row = blockIdx.x*4 + wave;
    if (row >= VSZ) return;
    const float* wr = W + (size_t)row*DIN;
    float s = 0.f;
    for (int i = lane; i < DIN; i += 64){ float v = wr[i]; s += v*v; }
    #pragma unroll
    for (int off = 32; off; off >>= 1) s += __shfl_down(s, off);
    if (lane == 0) invn[row] = 1.0f / sqrtf(s);
}

// ---------- generic fp32 NT-GEMM: C = act(A @ W^T + bias) ----------
// A: (M,K) row-major (or gathered rows from Atab via gidx), W: (N,K) row-major.
// Requires M%64==0, N%64==0, K%16==0.
template<int ACT>
__global__ __launch_bounds__(256) void k_gemm_nt(const float* __restrict__ A, const float* __restrict__ W,
                                                 const float* __restrict__ bias, float* __restrict__ C,
                                                 int M, int N, int K,
                                                 const int* __restrict__ gidx, const float* __restrict__ Atab){
    __shared__ float As[16][68];
    __shared__ float Ws[16][68];
    int tid = threadIdx.x;
    int bm = blockIdx.y*64, bn = blockIdx.x*64;
    int lr = tid >> 2;            // 0..63  (row within tile for loading)
    int lk = (tid & 3) * 4;       // 0,4,8,12
    int tr = (tid >> 4) * 4;      // 0..60  output row group
    int tc = (tid & 15) * 4;      // 0..60  output col group
    float acc[4][4] = {};
    int am = bm + lr;
    const float* Abase = gidx ? (Atab + (size_t)gidx[am]*K) : (A + (size_t)am*K);
    const float* Wbase = W + (size_t)(bn + lr)*K;
    for (int k0 = 0; k0 < K; k0 += 16){
        float4 av = *(const float4*)(Abase + k0 + lk);
        float4 wv = *(const float4*)(Wbase + k0 + lk);
        __syncthreads();
        As[lk+0][lr]=av.x; As[lk+1][lr]=av.y; As[lk+2][lr]=av.z; As[lk+3][lr]=av.w;
        Ws[lk+0][lr]=wv.x; Ws[lk+1][lr]=wv.y; Ws[lk+2][lr]=wv.z; Ws[lk+3][lr]=wv.w;
        __syncthreads();
        #pragma unroll
        for (int kk = 0; kk < 16; kk++){
            float4 a = *(const float4*)&As[kk][tr];
            float4 w = *(const float4*)&Ws[kk][tc];
            acc[0][0] += a.x*w.x; acc[0][1] += a.x*w.y; acc[0][2] += a.x*w.z; acc[0][3] += a.x*w.w;
            acc[1][0] += a.y*w.x; acc[1][1] += a.y*w.y; acc[1][2] += a.y*w.z; acc[1][3] += a.y*w.w;
            acc[2][0] += a.z*w.x; acc[2][1] += a.z*w.y; acc[2][2] += a.z*w.z; acc[2][3] += a.z*w.w;
            acc[3][0] += a.w*w.x; acc[3][1] += a.w*w.y; acc[3][2] += a.w*w.z; acc[3][3] += a.w*w.w;
        }
    }
    #pragma unroll
    for (int i = 0; i < 4; i++){
        #pragma unroll
        for (int j = 0; j < 4; j++){
            float v = acc[i][j];
            if (bias) v += bias[bn + tc + j];
            if (ACT == 1) v = tanhf(v);
            C[(size_t)(bm + tr + i)*N + bn + tc + j] = v;
        }
    }
}

// ---------- GRU elementwise combine ----------
__global__ __launch_bounds__(256) void k_gru(const float* __restrict__ gi, const float* __restrict__ gh,
                                             const float* __restrict__ hprev, float* __restrict__ hout){
    int idx = blockIdx.x*256 + threadIdx.x;   // b*H + j
    if (idx >= BB*H) return;
    int b = idx / H, j = idx % H;
    const float* gib = gi + (size_t)b*H3;
    const float* ghb = gh + (size_t)b*H3;
    float r = 1.f/(1.f + expf(-(gib[j]      + ghb[j])));
    float z = 1.f/(1.f + expf(-(gib[H + j]  + ghb[H + j])));
    float n = tanhf(gib[2*H + j] + r*ghb[2*H + j]);
    hout[idx] = (1.f - z)*n + z*hprev[idx];
}

// ---------- attention ----------
__global__ __launch_bounds__(256) void k_attn_scores(const float* __restrict__ ctx_p, const float* __restrict__ proj,
                                                     const float* __restrict__ v_att, float* __restrict__ scores){
    int wv = blockIdx.x*4 + (threadIdx.x >> 6);  // s*BB + b
    int lane = threadIdx.x & 63;
    int b = wv & (BB-1);
    const float* cp = ctx_p + (size_t)wv*H;
    const float* pj = proj + (size_t)b*H;
    float acc = 0.f;
    for (int h = lane; h < H; h += 64)
        acc += tanhf(cp[h] + pj[h]) * v_att[h];
    #pragma unroll
    for (int off = 32; off; off >>= 1) acc += __shfl_down(acc, off);
    if (lane == 0) scores[wv] = acc;
}

__global__ __launch_bounds__(256) void k_attn_soft_z(const float* __restrict__ scores, const float* __restrict__ mask,
                                                     const float* __restrict__ ctx, float* __restrict__ zt){
    __shared__ float alpha[SS];
    int b = blockIdx.x, tid = threadIdx.x;
    if (tid < SS){
        float sc = scores[tid*BB + b];
        if (!(mask[tid*BB + b] > 0.f)) sc += -1e9f;
        alpha[tid] = sc;
    }
    __syncthreads();
    if (tid < 64){
        float v = alpha[tid];
        float m = v;
        #pragma unroll
        for (int off = 32; off; off >>= 1) m = fmaxf(m, __shfl_xor(m, off));
        float e = expf(v - m);
        float sum = e;
        #pragma unroll
        for (int off = 32; off; off >>= 1) sum += __shfl_xor(sum, off);
        alpha[tid] = e / sum;
    }
    __syncthreads();
    for (int c = tid; c < H; c += 256){
        float acc = 0.f;
        #pragma unroll 4
        for (int s = 0; s < SS; s++) acc += alpha[s] * ctx[((size_t)s*BB + b)*H + c];
        zt[(size_t)b*H + c] = acc;
    }
}

// ---------- logit row-normalize ----------
__global__ __launch_bounds__(256) void k_logit_norm(float* __restrict__ logit){
    int row = blockIdx.x*4 + (threadIdx.x >> 6);
    int lane = threadIdx.x & 63;
    float* lr = logit + (size_t)row*DIN;
    float s = 0.f;
    for (int i = lane; i < DIN; i += 64){ float v = lr[i]; s += v*v; }
    #pragma unroll
    for (int off = 32; off; off >>= 1) s += __shfl_down(s, off);
    s = __shfl(s, 0);
    float inv = 1.0f / sqrtf(s);
    for (int i = lane; i < DIN; i += 64) lr[i] *= inv;
}

// ---------- fused final GEMM + per-row max (excluding tgt) + s_true ----------
// grid: (VCHUNKS=125, NROWS/32=188), block 256. Each block: 32 rows x 256 cols, K=512.
__global__ __launch_bounds__(256) void k_final(const float* __restrict__ logit, const float* __restrict__ Wout,
                                               const float* __restrict__ invn, const int* __restrict__ y,
                                               float* __restrict__ pmax, float* __restrict__ strue){
    __shared__ float As[32][DIN];     // 64 KB exactly
    int tid = threadIdx.x;
    int lane = tid & 63, wave = tid >> 6;
    int r0 = blockIdx.y*32;
    int n = blockIdx.x*256 + tid;
    {
        const float4* src = (const float4*)(logit + (size_t)r0*DIN);
        float4* dst = (float4*)&As[0][0];
        for (int i = tid; i < 32*DIN/4; i += 256) dst[i] = src[i];
    }
    __syncthreads();
    float acc[32];
    #pragma unroll
    for (int r = 0; r < 32; r++) acc[r] = 0.f;
    const float* wr = Wout + (size_t)n*DIN;
    for (int k0 = 0; k0 < DIN; k0 += 8){
        float4 w0 = *(const float4*)(wr + k0);
        float4 w1 = *(const float4*)(wr + k0 + 4);
        #pragma unroll
        for (int r = 0; r < 32; r++){
            float4 a0 = *(const float4*)&As[r][k0];
            float4 a1 = *(const float4*)&As[r][k0+4];
            acc[r] += a0.x*w0.x + a0.y*w0.y + a0.z*w0.z + a0.w*w0.w
                    + a1.x*w1.x + a1.y*w1.y + a1.z*w1.z + a1.w*w1.w;
        }
    }
    float inv = invn[n];
    __syncthreads();                       // done reading As; reuse as reduction scratch
    float* red = &As[0][0];                // [4 waves][32 rows]
    #pragma unroll
    for (int r = 0; r < 32; r++){
        float v = acc[r]*inv;
        int tgt = y[r0 + r + BB];
        if (n == tgt){ strue[r0 + r] = v; v = -1e30f; }
        #pragma unroll
        for (int off = 32; off; off >>= 1) v = fmaxf(v, __shfl_xor(v, off));
        if (lane == 0) red[wave*32 + r] = v;
    }
    __syncthreads();
    if (tid < 32){
        float m = fmaxf(fmaxf(red[tid], red[32 + tid]), fmaxf(red[64 + tid], red[96 + tid]));
        pmax[(size_t)(r0 + tid)*VCHUNKS + blockIdx.x] = m;
    }
}

__global__ __launch_bounds__(256) void k_loss(const float* __restrict__ pmax, const float* __restrict__ strue,
                                              const int* __restrict__ y, float* __restrict__ out){
    int R = blockIdx.x*256 + threadIdx.x;
    int lane = threadIdx.x & 63, wave = threadIdx.x >> 6;
    float l = 0.f;
    if (R < NROWS){
        int tgt = y[R + BB];
        if (tgt != 0){
            const float* pm = pmax + (size_t)R*VCHUNKS;
            float m = -1e30f;
            for (int i = 0; i < VCHUNKS; i++) m = fmaxf(m, pm[i]);
            l = fmaxf(FMARGIN - strue[R] + m, 0.f);
        }
    }
    #pragma unroll
    for (int off = 32; off; off >>= 1) l += __shfl_down(l, off);
    __shared__ float wsum[4];
    if (lane == 0) wsum[wave] = l;
    __syncthreads();
    if (threadIdx.x == 0) atomicAdd(out, wsum[0] + wsum[1] + wsum[2] + wsum[3]);
}

// ---------- launch ----------
extern "C" void kernel_launch(void* const* d_in, const int* in_sizes, int n_in,
                              void* d_out, int out_size, void* d_ws, size_t ws_size,
                              hipStream_t stream){
    const float* ctx    = (const float*)d_in[0];
    const float* mask   = (const float*)d_in[1];
    const int*   y      = (const int*)d_in[2];
    const float* emb_W  = (const float*)d_in[3];
    const float* W_init = (const float*)d_in[4];
    const float* b_init = (const float*)d_in[5];
    const float* W_ih0  = (const float*)d_in[6];
    const float* W_hh0  = (const float*)d_in[7];
    const float* b_ih0  = (const float*)d_in[8];
    const float* b_hh0  = (const float*)d_in[9];
    const float* W_c2c  = (const float*)d_in[10];
    const float* W_h2c  = (const float*)d_in[11];
    const float* v_att  = (const float*)d_in[12];
    const float* W_ih1  = (const float*)d_in[13];
    const float* W_hh1  = (const float*)d_in[14];
    const float* b_ih1  = (const float*)d_in[15];
    const float* b_hh1  = (const float*)d_in[16];
    const float* W_h2o  = (const float*)d_in[17];
    const float* b_h2o  = (const float*)d_in[18];
    const float* W_out  = (const float*)d_in[19];
    float* out = (float*)d_out;

    char* wsb = (char*)d_ws;
    size_t off = 0;
    auto alloc = [&](size_t nfloats)->float*{
        float* p = (float*)(wsb + off);
        off += ((nfloats*4) + 255) & ~(size_t)255;
        return p;
    };
    float* gi0_all = alloc((size_t)NROWS*H3);     // 73.9 MB
    float* ctx_p   = alloc((size_t)SS*BB*H);      // 33.5 MB
    float* h2_all  = alloc((size_t)NROWS*H);      // 24.6 MB
    float* logit   = alloc((size_t)NROWS*DIN);    // 12.3 MB
    float* invn    = alloc(VSZ);
    float* msum    = alloc(BB);
    float* meanc   = alloc((size_t)BB*H);
    float* h0      = alloc((size_t)BB*H);
    float* h1      = alloc((size_t)BB*H);
    float* gh0     = alloc((size_t)BB*H3);
    float* proj    = alloc((size_t)BB*H);
    float* scores  = alloc((size_t)SS*BB);
    float* zt      = alloc((size_t)BB*H);
    float* gi1     = alloc((size_t)BB*H3);
    float* gh1     = alloc((size_t)BB*H3);
    float* pmax    = alloc((size_t)NROWS*VCHUNKS);
    float* strue   = alloc(NROWS);

    hipMemsetAsync(d_out, 0, sizeof(float), stream);

    hipLaunchKernelGGL(k_mask_sum, dim3(1), dim3(128), 0, stream, mask, msum);
    hipLaunchKernelGGL(k_mean_ctx, dim3(BB*H/256), dim3(256), 0, stream, ctx, msum, meanc);
    hipLaunchKernelGGL((k_gemm_nt<1>), dim3(H/64, BB/64), dim3(256), 0, stream,
                       meanc, W_init, b_init, h0, BB, H, H, (const int*)nullptr, (const float*)nullptr);
    hipLaunchKernelGGL(k_wout_norm, dim3(VSZ/4), dim3(256), 0, stream, W_out, invn);
    hipLaunchKernelGGL((k_gemm_nt<0>), dim3(H3/64, NROWS/64), dim3(256), 0, stream,
                       (const float*)nullptr, W_ih0, b_ih0, gi0_all, NROWS, H3, DIN, y, emb_W);
    hipLaunchKernelGGL((k_gemm_nt<0>), dim3(H/64, SS*BB/64), dim3(256), 0, stream,
                       ctx, W_c2c, (const float*)nullptr, ctx_p, SS*BB, H, H, (const int*)nullptr, (const float*)nullptr);

    const float* hcur = h0;
    for (int t = 0; t < TP; t++){
        hipLaunchKernelGGL((k_gemm_nt<0>), dim3(H3/64, BB/64), dim3(256), 0, stream,
                           hcur, W_hh0, b_hh0, gh0, BB, H3, H, (const int*)nullptr, (const float*)nullptr);
        hipLaunchKernelGGL(k_gru, dim3(BB*H/256), dim3(256), 0, stream,
                           gi0_all + (size_t)t*BB*H3, gh0, hcur, h1);
        hipLaunchKernelGGL((k_gemm_nt<0>), dim3(H/64, BB/64), dim3(256), 0, stream,
                           h1, W_h2c, (const float*)nullptr, proj, BB, H, H, (const int*)nullptr, (const float*)nullptr);
        hipLaunchKernelGGL(k_attn_scores, dim3(SS*BB/4), dim3(256), 0, stream, ctx_p, proj, v_att, scores);
        hipLaunchKernelGGL(k_attn_soft_z, dim3(BB), dim3(256), 0, stream, scores, mask, ctx, zt);
        hipLaunchKernelGGL((k_gemm_nt<0>), dim3(H3/64, BB/64), dim3(256), 0, stream,
                           zt, W_ih1, b_ih1, gi1, BB, H3, H, (const int*)nullptr, (const float*)nullptr);
        hipLaunchKernelGGL((k_gemm_nt<0>), dim3(H3/64, BB/64), dim3(256), 0, stream,
                           h1, W_hh1, b_hh1, gh1, BB, H3, H, (const int*)nullptr, (const float*)nullptr);
        float* h2 = h2_all + (size_t)t*BB*H;
        hipLaunchKernelGGL(k_gru, dim3(BB*H/256), dim3(256), 0, stream, gi1, gh1, h1, h2);
        hcur = h2;
    }

    hipLaunchKernelGGL((k_gemm_nt<1>), dim3(DIN/64, NROWS/64), dim3(256), 0, stream,
                       h2_all, W_h2o, b_h2o, logit, NROWS, DIN, H, (const int*)nullptr, (const float*)nullptr);
    hipLaunchKernelGGL(k_logit_norm, dim3(NROWS/4), dim3(256), 0, stream, logit);
    hipLaunchKernelGGL(k_final, dim3(VCHUNKS, NROWS/32), dim3(256), 0, stream,
                       logit, W_out, invn, y, pmax, strue);
    hipLaunchKernelGGL(k_loss, dim3((NROWS + 255)/256), dim3(256), 0, stream, pmax, strue, y, out);
}

// Round 2
// 11017.578 us; speedup vs baseline: 1.6366x; 1.6366x over previous
//
#include <hip/hip_runtime.h>
#include <math.h>

#define H    1024
#define H3   3072
#define DIN  512
#define VSZ  32000
#define SS   64
#define BB   128
#define TP   47
#define NROWS (TP*BB)      // 6016
#define VCHUNKS 250        // 32000 / 128
#define FMARGIN 0.1f

typedef unsigned short u16;
typedef __bf16 bf16_t;
typedef bf16_t bf16x8 __attribute__((ext_vector_type(8)));
typedef float f32x4 __attribute__((ext_vector_type(4)));
typedef u16 u16x4 __attribute__((ext_vector_type(4)));
typedef u16 u16x8 __attribute__((ext_vector_type(8)));

__device__ inline u16 f2bf(float f){
    unsigned b = __float_as_uint(f);
    return (u16)((b + 0x7FFFu + ((b >> 16) & 1u)) >> 16);
}
__device__ inline float bf2f(u16 u){ return __uint_as_float(((unsigned)u) << 16); }

__device__ inline void stoval(float* p, float v){ *p = v; }
__device__ inline void stoval(u16* p, float v){ *p = f2bf(v); }

// ---------- small helpers ----------

__global__ __launch_bounds__(128) void k_mask_sum(const float* __restrict__ mask, float* __restrict__ msum){
    int b = threadIdx.x;
    if (b < BB){ float s = 0.f; for (int i = 0; i < SS; i++) s += mask[i*BB + b]; msum[b] = s; }
}

__global__ __launch_bounds__(256) void k_mean_ctx(const float* __restrict__ ctx, const float* __restrict__ msum,
                                                  float* __restrict__ mean){
    int idx = blockIdx.x*256 + threadIdx.x;
    if (idx < BB*H){
        float s = 0.f;
        for (int i = 0; i < SS; i++) s += ctx[(size_t)i*BB*H + idx];
        mean[idx] = s / msum[idx / H];
    }
}

__global__ __launch_bounds__(256) void k_f32bf(const float* __restrict__ in, u16* __restrict__ out, int n4){
    int i = blockIdx.x*256 + threadIdx.x;
    if (i >= n4) return;
    float4 v = ((const float4*)in)[i];
    u16x4 o = { f2bf(v.x), f2bf(v.y), f2bf(v.z), f2bf(v.w) };
    ((u16x4*)out)[i] = o;
}

// rows of length 512: L2-normalize + convert to bf16
__global__ __launch_bounds__(256) void k_rownorm_bf(const float* __restrict__ in, u16* __restrict__ out, int nrows){
    int w = threadIdx.x >> 6, lane = threadIdx.x & 63;
    int row = blockIdx.x*4 + w;
    if (row >= nrows) return;
    const float* r = in + (size_t)row*512 + lane*8;
    float4 a = *(const float4*)r;
    float4 b = *(const float4*)(r + 4);
    float s = a.x*a.x + a.y*a.y + a.z*a.z + a.w*a.w
            + b.x*b.x + b.y*b.y + b.z*b.z + b.w*b.w;
    #pragma unroll
    for (int off = 32; off; off >>= 1) s += __shfl_xor(s, off);
    float inv = rsqrtf(s);
    u16x8 o;
    o[0]=f2bf(a.x*inv); o[1]=f2bf(a.y*inv); o[2]=f2bf(a.z*inv); o[3]=f2bf(a.w*inv);
    o[4]=f2bf(b.x*inv); o[5]=f2bf(b.y*inv); o[6]=f2bf(b.z*inv); o[7]=f2bf(b.w*inv);
    *(u16x8*)(out + (size_t)row*512 + lane*8) = o;
}

// gather emb_W[y[row]] -> bf16 rows of 512
__global__ __launch_bounds__(256) void k_emb_bf(const float* __restrict__ emb, const int* __restrict__ y,
                                                u16* __restrict__ out){
    int w = threadIdx.x >> 6, lane = threadIdx.x & 63;
    int row = blockIdx.x*4 + w;            // < 6016 (grid 1504)
    int src = y[row];
    const float* r = emb + (size_t)src*512 + lane*8;
    float4 a = *(const float4*)r;
    float4 b = *(const float4*)(r + 4);
    u16x8 o;
    o[0]=f2bf(a.x); o[1]=f2bf(a.y); o[2]=f2bf(a.z); o[3]=f2bf(a.w);
    o[4]=f2bf(b.x); o[5]=f2bf(b.y); o[6]=f2bf(b.z); o[7]=f2bf(b.w);
    *(u16x8*)(out + (size_t)row*512 + lane*8) = o;
}

// ---------- legacy fp32 GEMM (used once for h0 init) ----------
template<int ACT>
__global__ __launch_bounds__(256) void k_gemm_nt(const float* __restrict__ A, const float* __restrict__ W,
                                                 const float* __restrict__ bias, float* __restrict__ C,
                                                 int M, int N, int K){
    __shared__ float As[16][68];
    __shared__ float Ws[16][68];
    int tid = threadIdx.x;
    int bm = blockIdx.y*64, bn = blockIdx.x*64;
    int lr = tid >> 2;
    int lk = (tid & 3) * 4;
    int tr = (tid >> 4) * 4;
    int tc = (tid & 15) * 4;
    float acc[4][4] = {};
    const float* Abase = A + (size_t)(bm + lr)*K;
    const float* Wbase = W + (size_t)(bn + lr)*K;
    for (int k0 = 0; k0 < K; k0 += 16){
        float4 av = *(const float4*)(Abase + k0 + lk);
        float4 wv = *(const float4*)(Wbase + k0 + lk);
        __syncthreads();
        As[lk+0][lr]=av.x; As[lk+1][lr]=av.y; As[lk+2][lr]=av.z; As[lk+3][lr]=av.w;
        Ws[lk+0][lr]=wv.x; Ws[lk+1][lr]=wv.y; Ws[lk+2][lr]=wv.z; Ws[lk+3][lr]=wv.w;
        __syncthreads();
        #pragma unroll
        for (int kk = 0; kk < 16; kk++){
            float4 a = *(const float4*)&As[kk][tr];
            float4 w = *(const float4*)&Ws[kk][tc];
            acc[0][0] += a.x*w.x; acc[0][1] += a.x*w.y; acc[0][2] += a.x*w.z; acc[0][3] += a.x*w.w;
            acc[1][0] += a.y*w.x; acc[1][1] += a.y*w.y; acc[1][2] += a.y*w.z; acc[1][3] += a.y*w.w;
            acc[2][0] += a.z*w.x; acc[2][1] += a.z*w.y; acc[2][2] += a.z*w.z; acc[2][3] += a.z*w.w;
            acc[3][0] += a.w*w.x; acc[3][1] += a.w*w.y; acc[3][2] += a.w*w.z; acc[3][3] += a.w*w.w;
        }
    }
    #pragma unroll
    for (int i = 0; i < 4; i++){
        #pragma unroll
        for (int j = 0; j < 4; j++){
            float v = acc[i][j];
            if (bias) v += bias[bn + tc + j];
            if (ACT == 1) v = tanhf(v);
            C[(size_t)(bm + tr + i)*N + bn + tc + j] = v;
        }
    }
}

// ---------- bf16 MFMA GEMM: C = [tanh](A @ W^T + bias) ----------
// A: (M,K) bf16 row-major, W: (N,K) bf16 row-major. M % (BM_WAVES*WM) == 0 etc.
template<int BM_WAVES, int BN_WAVES, int WM, int WN, int ACT, typename OutT>
__global__ __launch_bounds__(BM_WAVES*BN_WAVES*64)
void k_bgemm(const u16* __restrict__ A, const u16* __restrict__ W,
             const float* __restrict__ bias, OutT* __restrict__ C,
             int M, int N, int K){
    constexpr int MF = WM/16, NF = WN/16;
    int tid = threadIdx.x;
    int w = tid >> 6, lane = tid & 63;
    int wm = w / BN_WAVES, wn = w % BN_WAVES;
    int row0 = blockIdx.y*(BM_WAVES*WM) + wm*WM;
    int col0 = blockIdx.x*(BN_WAVES*WN) + wn*WN;
    int r16 = lane & 15, kg = (lane >> 4) * 8;
    const u16* Ab = A + (size_t)(row0 + r16)*K + kg;
    const u16* Wb = W + (size_t)(col0 + r16)*K + kg;
    f32x4 acc[MF][NF] = {};
    for (int k0 = 0; k0 < K; k0 += 32){
        bf16x8 af[MF], bfv[NF];
        #pragma unroll
        for (int i = 0; i < MF; i++) af[i] = *(const bf16x8*)(Ab + (size_t)i*16*K + k0);
        #pragma unroll
        for (int j = 0; j < NF; j++) bfv[j] = *(const bf16x8*)(Wb + (size_t)j*16*K + k0);
        #pragma unroll
        for (int i = 0; i < MF; i++)
            #pragma unroll
            for (int j = 0; j < NF; j++)
                acc[i][j] = __builtin_amdgcn_mfma_f32_16x16x32_bf16(af[i], bfv[j], acc[i][j], 0, 0, 0);
    }
    int rg = (lane >> 4) * 4;
    #pragma unroll
    for (int i = 0; i < MF; i++){
        #pragma unroll
        for (int j = 0; j < NF; j++){
            #pragma unroll
            for (int r = 0; r < 4; r++){
                int row = row0 + i*16 + rg + r;
                int col = col0 + j*16 + r16;
                float v = acc[i][j][r];
                if (bias) v += bias[col];
                if (ACT) v = tanhf(v);
                stoval(C + (size_t)row*N + col, v);
            }
        }
    }
}

// ---------- GRU elementwise combine (bf16 or f32 gi) ----------
__global__ __launch_bounds__(256) void k_gru(const u16* __restrict__ gib, const float* __restrict__ gif, int si,
                                             const float* __restrict__ gh, int sh,
                                             const float* __restrict__ bi, const float* __restrict__ bh,
                                             const float* __restrict__ hprev, float* __restrict__ hf,
                                             u16* __restrict__ hbf){
    int idx = blockIdx.x*256 + threadIdx.x;     // < BB*H
    int b = idx >> 10, j = idx & 1023;
    size_t gio = (size_t)b*si + j;
    float gr, gz, gn;
    if (gib){ gr = bf2f(gib[gio]); gz = bf2f(gib[gio + H]); gn = bf2f(gib[gio + 2*H]); }
    else    { gr = gif[gio];       gz = gif[gio + H];       gn = gif[gio + 2*H]; }
    gr += bi[j]; gz += bi[H + j]; gn += bi[2*H + j];
    size_t gho = (size_t)b*sh + j;
    float hr = gh[gho] + bh[j];
    float hz = gh[gho + H] + bh[H + j];
    float hn = gh[gho + 2*H] + bh[2*H + j];
    float rr = 1.f/(1.f + expf(-(gr + hr)));
    float zz = 1.f/(1.f + expf(-(gz + hz)));
    float nn = tanhf(gn + rr*hn);
    float hv = (1.f - zz)*nn + zz*hprev[idx];
    hf[idx] = hv;
    hbf[idx] = f2bf(hv);
}

// ---------- fused attention: scores + softmax + z_t (bf16 out) ----------
__global__ __launch_bounds__(256) void k_attn(const u16* __restrict__ ctxp, const float* __restrict__ pg,
                                              const float* __restrict__ v_att, const float* __restrict__ mask,
                                              const float* __restrict__ ctx, u16* __restrict__ ztb){
    __shared__ float sal[SS];
    int b = blockIdx.x, tid = threadIdx.x;
    int w = tid >> 6, lane = tid & 63;
    const float* proj = pg + (size_t)b*4096;
    for (int s = w*16; s < w*16 + 16; s++){
        const u16* cp = ctxp + ((size_t)s*BB + b)*H;
        float acc = 0.f;
        for (int h = lane; h < H; h += 64)
            acc += tanhf(bf2f(cp[h]) + proj[h]) * v_att[h];
        #pragma unroll
        for (int off = 32; off; off >>= 1) acc += __shfl_xor(acc, off);
        if (lane == 0) sal[s] = (mask[s*BB + b] > 0.f) ? acc : acc - 1e9f;
    }
    __syncthreads();
    if (tid < 64){
        float v = sal[tid];
        float m = v;
        #pragma unroll
        for (int off = 32; off; off >>= 1) m = fmaxf(m, __shfl_xor(m, off));
        float e = expf(v - m);
        float sum = e;
        #pragma unroll
        for (int off = 32; off; off >>= 1) sum += __shfl_xor(sum, off);
        sal[tid] = e / sum;
    }
    __syncthreads();
    int c0 = tid*4;
    float a0 = 0.f, a1 = 0.f, a2 = 0.f, a3 = 0.f;
    for (int s = 0; s < SS; s++){
        float al = sal[s];
        float4 cv = *(const float4*)(ctx + ((size_t)s*BB + b)*H + c0);
        a0 += al*cv.x; a1 += al*cv.y; a2 += al*cv.z; a3 += al*cv.w;
    }
    u16x4 o = { f2bf(a0), f2bf(a1), f2bf(a2), f2bf(a3) };
    *(u16x4*)(ztb + (size_t)b*H + c0) = o;
}

// ---------- fused final GEMM (bf16 MFMA) + row-max (excl tgt) + s_true ----------
// grid (47, 250): x = row tile of 128, y = vocab chunk of 128
__global__ __launch_bounds__(256) void k_final(const u16* __restrict__ logitb, const u16* __restrict__ Wn,
                                               const int* __restrict__ y, float* __restrict__ pmax,
                                               float* __restrict__ strue){
    __shared__ float red[128][2];
    int tid = threadIdx.x, w = tid >> 6, lane = tid & 63;
    int wm = w >> 1, wn = w & 1;
    int row0 = blockIdx.x*128 + wm*64;
    int col0 = blockIdx.y*128 + wn*64;
    int r16 = lane & 15, kg = (lane >> 4)*8, rg = (lane >> 4)*4;
    const u16* Ab = logitb + (size_t)(row0 + r16)*DIN + kg;
    const u16* Wb = Wn + (size_t)(col0 + r16)*DIN + kg;
    f32x4 acc[4][4] = {};
    for (int k0 = 0; k0 < DIN; k0 += 32){
        bf16x8 af[4], bfv[4];
        #pragma unroll
        for (int i = 0; i < 4; i++) af[i] = *(const bf16x8*)(Ab + (size_t)i*16*DIN + k0);
        #pragma unroll
        for (int j = 0; j < 4; j++) bfv[j] = *(const bf16x8*)(Wb + (size_t)j*16*DIN + k0);
        #pragma unroll
        for (int i = 0; i < 4; i++)
            #pragma unroll
            for (int j = 0; j < 4; j++)
                acc[i][j] = __builtin_amdgcn_mfma_f32_16x16x32_bf16(af[i], bfv[j], acc[i][j], 0, 0, 0);
    }
    #pragma unroll
    for (int i = 0; i < 4; i++){
        #pragma unroll
        for (int r = 0; r < 4; r++){
            int row = row0 + i*16 + rg + r;
            int tgt = y[row + BB];
            float m = -1e30f;
            #pragma unroll
            for (int j = 0; j < 4; j++){
                float v = acc[i][j][r];
                int col = col0 + j*16 + r16;
                if (col == tgt){ strue[row] = v; v = -1e30f; }
                m = fmaxf(m, v);
            }
            m = fmaxf(m, __shfl_xor(m, 1));
            m = fmaxf(m, __shfl_xor(m, 2));
            m = fmaxf(m, __shfl_xor(m, 4));
            m = fmaxf(m, __shfl_xor(m, 8));
            if (r16 == 0) red[wm*64 + i*16 + rg + r][wn] = m;
        }
    }
    __syncthreads();
    if (tid < 128){
        float m = fmaxf(red[tid][0], red[tid][1]);
        pmax[(size_t)(blockIdx.x*128 + tid)*VCHUNKS + blockIdx.y] = m;
    }
}

__global__ __launch_bounds__(256) void k_loss(const float* __restrict__ pmax, const float* __restrict__ strue,
                                              const int* __restrict__ y, float* __restrict__ out){
    int R = blockIdx.x*256 + threadIdx.x;
    int lane = threadIdx.x & 63, wave = threadIdx.x >> 6;
    float l = 0.f;
    if (R < NROWS){
        int tgt = y[R + BB];
        if (tgt != 0){
            const float* pm = pmax + (size_t)R*VCHUNKS;
            float m = -1e30f;
            for (int i = 0; i < VCHUNKS; i++) m = fmaxf(m, pm[i]);
            l = fmaxf(FMARGIN - strue[R] + m, 0.f);
        }
    }
    #pragma unroll
    for (int off = 32; off; off >>= 1) l += __shfl_down(l, off);
    __shared__ float wsum[4];
    if (lane == 0) wsum[wave] = l;
    __syncthreads();
    if (threadIdx.x == 0) atomicAdd(out, wsum[0] + wsum[1] + wsum[2] + wsum[3]);
}

// ---------- launch ----------
extern "C" void kernel_launch(void* const* d_in, const int* in_sizes, int n_in,
                              void* d_out, int out_size, void* d_ws, size_t ws_size,
                              hipStream_t stream){
    const float* ctx    = (const float*)d_in[0];
    const float* mask   = (const float*)d_in[1];
    const int*   y      = (const int*)d_in[2];
    const float* emb_W  = (const float*)d_in[3];
    const float* W_init = (const float*)d_in[4];
    const float* b_init = (const float*)d_in[5];
    const float* W_ih0  = (const float*)d_in[6];
    const float* W_hh0  = (const float*)d_in[7];
    const float* b_ih0  = (const float*)d_in[8];
    const float* b_hh0  = (const float*)d_in[9];
    const float* W_c2c  = (const float*)d_in[10];
    const float* W_h2c  = (const float*)d_in[11];
    const float* v_att  = (const float*)d_in[12];
    const float* W_ih1  = (const float*)d_in[13];
    const float* W_hh1  = (const float*)d_in[14];
    const float* b_ih1  = (const float*)d_in[15];
    const float* b_hh1  = (const float*)d_in[16];
    const float* W_h2o  = (const float*)d_in[17];
    const float* b_h2o  = (const float*)d_in[18];
    const float* W_out  = (const float*)d_in[19];
    float* out = (float*)d_out;

    char* wsb = (char*)d_ws;
    size_t off = 0;
    auto alloc = [&](size_t bytes)->void*{
        void* p = (void*)(wsb + off);
        off = (off + bytes + 255) & ~(size_t)255;
        return p;
    };
    u16* Wih0b  = (u16*)alloc((size_t)H3*DIN*2);
    u16* Whh0b  = (u16*)alloc((size_t)H3*H*2);
    u16* Wcatb  = (u16*)alloc((size_t)4096*H*2);
    u16* Wih1b  = (u16*)alloc((size_t)H3*H*2);
    u16* Wh2ob  = (u16*)alloc((size_t)DIN*H*2);
    u16* Wc2cb  = (u16*)alloc((size_t)H*H*2);
    u16* Woutb  = (u16*)alloc((size_t)VSZ*DIN*2);
    u16* ctxb   = (u16*)alloc((size_t)SS*BB*H*2);
    u16* ctxpb  = (u16*)alloc((size_t)SS*BB*H*2);
    u16* gi0b   = (u16*)alloc((size_t)NROWS*H3*2);     // 37 MB; reused later as logit f32 (12.3 MB)
    u16* embb   = (u16*)alloc((size_t)NROWS*DIN*2);    // 6.2 MB; reused later as pmax f32 (6.0 MB)
    u16* h2allb = (u16*)alloc((size_t)NROWS*H*2);
    u16* logitb = (u16*)alloc((size_t)NROWS*DIN*2);
    float* strue = (float*)alloc(NROWS*4);
    float* msum  = (float*)alloc(BB*4);
    float* meanc = (float*)alloc((size_t)BB*H*4);
    float* h0f   = (float*)alloc((size_t)BB*H*4);
    u16*   h0b   = (u16*)alloc((size_t)BB*H*2);
    float* gh0   = (float*)alloc((size_t)BB*H3*4);
    float* pg    = (float*)alloc((size_t)BB*4096*4);
    float* gi1   = (float*)alloc((size_t)BB*H3*4);
    float* hA    = (float*)alloc((size_t)BB*H*4);
    float* hB    = (float*)alloc((size_t)BB*H*4);
    float* h1f   = (float*)alloc((size_t)BB*H*4);
    u16*   h1b   = (u16*)alloc((size_t)BB*H*2);
    u16*   ztb   = (u16*)alloc((size_t)BB*H*2);

    float* logitf = (float*)gi0b;   // alias: gi0 dead after recurrence
    float* pmax   = (float*)embb;   // alias: emb dead after gi0 GEMM

    hipMemsetAsync(d_out, 0, sizeof(float), stream);

    // init: converts + h0 + batched GEMMs
    hipLaunchKernelGGL(k_mask_sum, dim3(1), dim3(128), 0, stream, mask, msum);
    hipLaunchKernelGGL(k_mean_ctx, dim3(BB*H/256), dim3(256), 0, stream, ctx, msum, meanc);
    hipLaunchKernelGGL((k_gemm_nt<1>), dim3(H/64, BB/64), dim3(256), 0, stream,
                       meanc, W_init, b_init, h0f, BB, H, H);
    hipLaunchKernelGGL(k_f32bf, dim3(BB*H/4/256), dim3(256), 0, stream, h0f, h0b, BB*H/4);
    hipLaunchKernelGGL(k_f32bf, dim3((H3*DIN/4+255)/256), dim3(256), 0, stream, W_ih0, Wih0b, H3*DIN/4);
    hipLaunchKernelGGL(k_f32bf, dim3((H3*H/4+255)/256), dim3(256), 0, stream, W_hh0, Whh0b, H3*H/4);
    hipLaunchKernelGGL(k_f32bf, dim3((H*H/4+255)/256), dim3(256), 0, stream, W_c2c, Wc2cb, H*H/4);
    hipLaunchKernelGGL(k_f32bf, dim3((H*H/4+255)/256), dim3(256), 0, stream, W_h2c, Wcatb, H*H/4);
    hipLaunchKernelGGL(k_f32bf, dim3((H3*H/4+255)/256), dim3(256), 0, stream, W_hh1, Wcatb + (size_t)H*H, H3*H/4);
    hipLaunchKernelGGL(k_f32bf, dim3((H3*H/4+255)/256), dim3(256), 0, stream, W_ih1, Wih1b, H3*H/4);
    hipLaunchKernelGGL(k_f32bf, dim3((DIN*H/4+255)/256), dim3(256), 0, stream, W_h2o, Wh2ob, DIN*H/4);
    hipLaunchKernelGGL(k_f32bf, dim3((SS*BB*H/4+255)/256), dim3(256), 0, stream, ctx, ctxb, SS*BB*H/4);
    hipLaunchKernelGGL(k_rownorm_bf, dim3(VSZ/4), dim3(256), 0, stream, W_out, Woutb, VSZ);
    hipLaunchKernelGGL(k_emb_bf, dim3(NROWS/4), dim3(256), 0, stream, emb_W, y, embb);
    // gi0_all = emb @ W_ih0^T  (bf16 out)
    hipLaunchKernelGGL((k_bgemm<2,2,64,64,0,u16>), dim3(H3/128, NROWS/128), dim3(256), 0, stream,
                       embb, Wih0b, (const float*)nullptr, gi0b, NROWS, H3, DIN);
    // ctx_p = ctx @ W_c2c^T  (bf16 out)
    hipLaunchKernelGGL((k_bgemm<2,2,64,64,0,u16>), dim3(H/128, SS*BB/128), dim3(256), 0, stream,
                       ctxb, Wc2cb, (const float*)nullptr, ctxpb, SS*BB, H, H);

    // recurrence
    const float* hcf = h0f;
    const u16*   hcb = h0b;
    for (int t = 0; t < TP; t++){
        hipLaunchKernelGGL((k_bgemm<1,4,32,64,0,float>), dim3(H3/256, BB/32), dim3(256), 0, stream,
                           hcb, Whh0b, (const float*)nullptr, gh0, BB, H3, H);
        hipLaunchKernelGGL(k_gru, dim3(BB*H/256), dim3(256), 0, stream,
                           gi0b + (size_t)t*BB*H3, (const float*)nullptr, H3, gh0, H3,
                           b_ih0, b_hh0, hcf, h1f, h1b);
        hipLaunchKernelGGL((k_bgemm<1,4,32,64,0,float>), dim3(4096/256, BB/32), dim3(256), 0, stream,
                           h1b, Wcatb, (const float*)nullptr, pg, BB, 4096, H);
        hipLaunchKernelGGL(k_attn, dim3(BB), dim3(256), 0, stream, ctxpb, pg, v_att, mask, ctx, ztb);
        hipLaunchKernelGGL((k_bgemm<1,4,32,64,0,float>), dim3(H3/256, BB/32), dim3(256), 0, stream,
                           ztb, Wih1b, (const float*)nullptr, gi1, BB, H3, H);
        float* h2f = (t & 1) ? hB : hA;
        u16*   h2b = h2allb + (size_t)t*BB*H;
        hipLaunchKernelGGL(k_gru, dim3(BB*H/256), dim3(256), 0, stream,
                           (const u16*)nullptr, gi1, H3, pg + H, 4096,
                           b_ih1, b_hh1, h1f, h2f, h2b);
        hcf = h2f; hcb = h2b;
    }

    // output head
    hipLaunchKernelGGL((k_bgemm<2,2,64,64,1,float>), dim3(DIN/128, NROWS/128), dim3(256), 0, stream,
                       h2allb, Wh2ob, b_h2o, logitf, NROWS, DIN, H);
    hipLaunchKernelGGL(k_rownorm_bf, dim3(NROWS/4), dim3(256), 0, stream, logitf, logitb, NROWS);
    hipLaunchKernelGGL(k_final, dim3(NROWS/128, VSZ/128), dim3(256), 0, stream,
                       logitb, Woutb, y, pmax, strue);
    hipLaunchKernelGGL(k_loss, dim3((NROWS + 255)/256), dim3(256), 0, stream, pmax, strue, y, out);
}